// Round 1
// baseline (6548.843 us; speedup 1.0000x reference)
//
#include <hip/hip_runtime.h>

#define HID 128
#define NPB1 16   // nodes per block, linear1
#define NPB2 8    // nodes per block, linear2

// ---------------- index dtype detection + conversion ----------------
__global__ void detect_kernel(const unsigned int* __restrict__ p, int* __restrict__ flag) {
    if (threadIdx.x == 0 && blockIdx.x == 0) {
        int is64 = 1;
        for (int i = 0; i < 64; ++i) {
            if (p[2 * i + 1] != 0u) { is64 = 0; break; }
        }
        *flag = is64;
    }
}

__global__ void cvt_kernel(const void* __restrict__ p, int* __restrict__ out, int n,
                           const int* __restrict__ flag) {
    int i = blockIdx.x * blockDim.x + threadIdx.x;
    if (i < n) {
        out[i] = (*flag) ? (int)((const long long*)p)[i] : ((const int*)p)[i];
    }
}

// ---------------- zeroing (graph-capture-safe, no memset) ----------------
__global__ void zero_kernel(float4* __restrict__ p, long long n4) {
    long long i = (long long)blockIdx.x * blockDim.x + threadIdx.x;
    long long stride = (long long)gridDim.x * blockDim.x;
    for (; i < n4; i += stride) p[i] = make_float4(0.f, 0.f, 0.f, 0.f);
}

// ---------------- degree + dinv ----------------
__global__ void deg_kernel(const int* __restrict__ dst, int* __restrict__ deg, int E) {
    int i = blockIdx.x * blockDim.x + threadIdx.x;
    if (i < E) atomicAdd(&deg[dst[i]], 1);
}

__global__ void dinv_kernel(const int* __restrict__ deg, float* __restrict__ dinv, int N) {
    int i = blockIdx.x * blockDim.x + threadIdx.x;
    if (i < N) dinv[i] = rsqrtf((float)(deg[i] + 1));  // +1 = self loop
}

// ---------------- linear1: h = x @ W1   (x: [N,20], W1: [20,128]) ----------------
__global__ __launch_bounds__(HID) void linear1_kernel(const float* __restrict__ x,
                                                      const float* __restrict__ W,
                                                      float* __restrict__ h, int N, int IN) {
    __shared__ float Ws[20 * HID];
    __shared__ float xs[NPB1][20];
    for (int i = threadIdx.x; i < IN * HID; i += blockDim.x) Ws[i] = W[i];
    int n0 = blockIdx.x * NPB1;
    for (int i = threadIdx.x; i < NPB1 * IN; i += blockDim.x) {
        int m = i / IN, k = i % IN;
        int n = n0 + m;
        xs[m][k] = (n < N) ? x[(size_t)n * IN + k] : 0.f;
    }
    __syncthreads();
    int j = threadIdx.x;
    for (int m = 0; m < NPB1; ++m) {
        int n = n0 + m;
        if (n >= N) break;
        float acc = 0.f;
#pragma unroll 20
        for (int k = 0; k < 20; ++k) acc += xs[m][k] * Ws[k * HID + j];
        h[(size_t)n * HID + j] = acc;
    }
}

// ---------------- linear2: h2 = h @ W2   (W2: [128,128]) ----------------
__global__ __launch_bounds__(HID) void linear2_kernel(const float* __restrict__ hin,
                                                      const float* __restrict__ W,
                                                      float* __restrict__ hout, int N) {
    __shared__ float Ws[HID * HID];  // 64 KiB
    __shared__ float xs[NPB2][HID];
    for (int i = threadIdx.x; i < HID * HID; i += blockDim.x) Ws[i] = W[i];
    int n0 = blockIdx.x * NPB2;
    for (int i = threadIdx.x; i < NPB2 * HID; i += blockDim.x) {
        int m = i >> 7, k = i & 127;
        int n = n0 + m;
        xs[m][k] = (n < N) ? hin[(size_t)n * HID + k] : 0.f;
    }
    __syncthreads();
    int j = threadIdx.x;
    for (int m = 0; m < NPB2; ++m) {
        int n = n0 + m;
        if (n >= N) break;
        float acc = 0.f;
#pragma unroll 16
        for (int k = 0; k < HID; ++k) acc += xs[m][k] * Ws[k * HID + j];
        hout[(size_t)n * HID + j] = acc;
    }
}

// ---------------- edge aggregation: agg[dst] += h[src] * norm ----------------
__global__ void agg_kernel(const float* __restrict__ h, float* __restrict__ agg,
                           const int* __restrict__ src, const int* __restrict__ dst,
                           const float* __restrict__ dinv, int E) {
    int t = blockIdx.x * blockDim.x + threadIdx.x;
    int e = t >> 5;
    if (e >= E) return;
    int q = t & 31;
    int s = src[e], d = dst[e];
    float nm = dinv[s] * dinv[d];
    float4 v = ((const float4*)(h + (size_t)s * HID))[q];
    float* o = agg + (size_t)d * HID + (size_t)q * 4;
    atomicAdd(o + 0, v.x * nm);
    atomicAdd(o + 1, v.y * nm);
    atomicAdd(o + 2, v.z * nm);
    atomicAdd(o + 3, v.w * nm);
}

// ---------------- bias + self-loop + relu (in place on agg) ----------------
__global__ void brs_kernel(float* __restrict__ agg, const float* __restrict__ h,
                           const float* __restrict__ b, const float* __restrict__ dinv, int N) {
    int t = blockIdx.x * blockDim.x + threadIdx.x;
    if (t >= N * HID) return;
    int n = t >> 7, j = t & 127;
    float di = dinv[n];
    float v = agg[t] + h[t] * di * di + b[j];
    agg[t] = v > 0.f ? v : 0.f;
}

// ---------------- pooling ----------------
__global__ void pool_kernel(const float* __restrict__ h, const int* __restrict__ batch,
                            float* __restrict__ pooled, int N) {
    int t = blockIdx.x * blockDim.x + threadIdx.x;
    if (t >= N * HID) return;
    int n = t >> 7, j = t & 127;
    atomicAdd(&pooled[(size_t)batch[n] * HID + j], h[t]);
}

__global__ void cnt_kernel(const int* __restrict__ batch, float* __restrict__ cnt, int N) {
    int i = blockIdx.x * blockDim.x + threadIdx.x;
    if (i < N) atomicAdd(&cnt[batch[i]], 1.f);
}

__global__ void mean_kernel(const float* __restrict__ pooled, const float* __restrict__ cnt,
                            float* __restrict__ meanp, int G) {
    int t = blockIdx.x * blockDim.x + threadIdx.x;
    if (t >= G * HID) return;
    int g = t >> 7;
    meanp[t] = pooled[t] / fmaxf(cnt[g], 1.f);
}

// ---------------- classifier: out = meanp @ Wc + bc ----------------
#define TILE_G 32
__global__ __launch_bounds__(256) void classifier_kernel(const float* __restrict__ meanp,
                                                         const float* __restrict__ Wc,
                                                         const float* __restrict__ bc,
                                                         float* __restrict__ out, int G, int OUT) {
    __shared__ float ps[TILE_G * HID];  // 16 KiB
    int g0 = blockIdx.y * TILE_G;
    for (int i = threadIdx.x; i < TILE_G * HID; i += blockDim.x) {
        int g = g0 + (i >> 7);
        ps[i] = (g < G) ? meanp[(size_t)g * HID + (i & 127)] : 0.f;
    }
    __syncthreads();
    int o = blockIdx.x * blockDim.x + threadIdx.x;
    if (o >= OUT) return;
    float acc[TILE_G];
#pragma unroll
    for (int g = 0; g < TILE_G; ++g) acc[g] = 0.f;
    for (int k = 0; k < HID; ++k) {
        float w = Wc[(size_t)k * OUT + o];
#pragma unroll
        for (int g = 0; g < TILE_G; ++g) acc[g] += ps[g * HID + k] * w;
    }
    float b = bc[o];
    for (int g = 0; g < TILE_G && (g0 + g) < G; ++g)
        out[(size_t)(g0 + g) * OUT + o] = acc[g] + b;
}

// ---------------- launch ----------------
extern "C" void kernel_launch(void* const* d_in, const int* in_sizes, int n_in,
                              void* d_out, int out_size, void* d_ws, size_t ws_size,
                              hipStream_t stream) {
    const float* x  = (const float*)d_in[0];
    const void*  ei = d_in[1];
    const void*  bt = d_in[2];
    const float* W1 = (const float*)d_in[3];
    const float* b1 = (const float*)d_in[4];
    const float* W2 = (const float*)d_in[5];
    const float* b2 = (const float*)d_in[6];
    const float* Wc = (const float*)d_in[7];
    const float* bc = (const float*)d_in[8];
    float* out = (float*)d_out;

    const int N   = in_sizes[2];
    const int E   = in_sizes[1] / 2;
    const int IN  = in_sizes[0] / N;
    const int OUT = in_sizes[8];
    const int G   = out_size / OUT;

    // workspace layout
    char* ws = (char*)d_ws;
    size_t off = 0;
    auto alloc = [&](size_t bytes) {
        size_t p = off;
        off += (bytes + 255) & ~(size_t)255;
        return p;
    };
    int*   idx32   = (int*)(ws + alloc((size_t)2 * E * 4));
    int*   batch32 = (int*)(ws + alloc((size_t)N * 4));
    int*   deg     = (int*)(ws + alloc((size_t)N * 4));
    float* dinv    = (float*)(ws + alloc((size_t)N * 4));
    float* bufA    = (float*)(ws + alloc((size_t)N * HID * 4));
    float* bufB    = (float*)(ws + alloc((size_t)N * HID * 4));
    float* pooled  = (float*)(ws + alloc((size_t)G * HID * 4));
    float* cnt     = (float*)(ws + alloc((size_t)G * 4));
    float* meanp   = (float*)(ws + alloc((size_t)G * HID * 4));
    int*   flag    = (int*)(ws + alloc(4));
    (void)ws_size;

    int* srcI = idx32;
    int* dstI = idx32 + E;

    const int B = 256;

    // 1. detect index dtype, convert to int32
    detect_kernel<<<1, 64, 0, stream>>>((const unsigned int*)ei, flag);
    cvt_kernel<<<(2 * E + B - 1) / B, B, 0, stream>>>(ei, idx32, 2 * E, flag);
    cvt_kernel<<<(N + B - 1) / B, B, 0, stream>>>(bt, batch32, N, flag);

    // 2. degrees (+1 self loop) -> dinv
    zero_kernel<<<2048, B, 0, stream>>>((float4*)deg, (long long)N / 4);
    deg_kernel<<<(E + B - 1) / B, B, 0, stream>>>(dstI, deg, E);
    dinv_kernel<<<(N + B - 1) / B, B, 0, stream>>>(deg, dinv, N);

    // 3. layer 1
    linear1_kernel<<<(N + NPB1 - 1) / NPB1, HID, 0, stream>>>(x, W1, bufA, N, IN);
    zero_kernel<<<4096, B, 0, stream>>>((float4*)bufB, (long long)N * HID / 4);
    {
        long long tot = (long long)E * 32;
        agg_kernel<<<(unsigned)((tot + B - 1) / B), B, 0, stream>>>(bufA, bufB, srcI, dstI, dinv, E);
    }
    brs_kernel<<<(N * HID + B - 1) / B, B, 0, stream>>>(bufB, bufA, b1, dinv, N);

    // 4. layer 2
    linear2_kernel<<<(N + NPB2 - 1) / NPB2, HID, 0, stream>>>(bufB, W2, bufA, N);
    zero_kernel<<<4096, B, 0, stream>>>((float4*)bufB, (long long)N * HID / 4);
    {
        long long tot = (long long)E * 32;
        agg_kernel<<<(unsigned)((tot + B - 1) / B), B, 0, stream>>>(bufA, bufB, srcI, dstI, dinv, E);
    }
    brs_kernel<<<(N * HID + B - 1) / B, B, 0, stream>>>(bufB, bufA, b2, dinv, N);

    // 5. mean pool
    zero_kernel<<<64, B, 0, stream>>>((float4*)pooled, (long long)G * HID / 4);
    zero_kernel<<<1, B, 0, stream>>>((float4*)cnt, (long long)G / 4);
    pool_kernel<<<(N * HID + B - 1) / B, B, 0, stream>>>(bufB, batch32, pooled, N);
    cnt_kernel<<<(N + B - 1) / B, B, 0, stream>>>(batch32, cnt, N);
    mean_kernel<<<(G * HID + B - 1) / B, B, 0, stream>>>(pooled, cnt, meanp, G);

    // 6. classifier
    {
        dim3 grid((OUT + 255) / 256, (G + TILE_G - 1) / TILE_G);
        classifier_kernel<<<grid, 256, 0, stream>>>(meanp, Wc, bc, out, G, OUT);
    }
}

// Round 2
// 1540.057 us; speedup vs baseline: 4.2523x; 4.2523x over previous
//
#include <hip/hip_runtime.h>

#define HID 128
#define NPB1 16   // nodes per block, linear1
#define NPB2 8    // nodes per block, linear2
#define SCAN_B 256

// ---------------- index dtype detection + conversion ----------------
__global__ void detect_kernel(const unsigned int* __restrict__ p, int* __restrict__ flag) {
    if (threadIdx.x == 0 && blockIdx.x == 0) {
        int is64 = 1;
        for (int i = 0; i < 64; ++i) {
            if (p[2 * i + 1] != 0u) { is64 = 0; break; }
        }
        *flag = is64;
    }
}

__global__ void cvt_kernel(const void* __restrict__ p, int* __restrict__ out, int n,
                           const int* __restrict__ flag) {
    int i = blockIdx.x * blockDim.x + threadIdx.x;
    if (i < n) {
        out[i] = (*flag) ? (int)((const long long*)p)[i] : ((const int*)p)[i];
    }
}

// ---------------- zeroing (graph-capture-safe, no memset) ----------------
__global__ void zero_kernel(float4* __restrict__ p, long long n4) {
    long long i = (long long)blockIdx.x * blockDim.x + threadIdx.x;
    long long stride = (long long)gridDim.x * blockDim.x;
    for (; i < n4; i += stride) p[i] = make_float4(0.f, 0.f, 0.f, 0.f);
}

// ---------------- degree + dinv ----------------
__global__ void deg_kernel(const int* __restrict__ dst, int* __restrict__ deg, int E) {
    int i = blockIdx.x * blockDim.x + threadIdx.x;
    if (i < E) atomicAdd(&deg[dst[i]], 1);
}

__global__ void dinv_kernel(const int* __restrict__ deg, float* __restrict__ dinv, int N) {
    int i = blockIdx.x * blockDim.x + threadIdx.x;
    if (i < N) dinv[i] = rsqrtf((float)(deg[i] + 1));  // +1 = self loop
}

// ---------------- exclusive scan (3 kernels) ----------------
__global__ __launch_bounds__(SCAN_B) void scan1_kernel(const int* __restrict__ deg,
                                                       int* __restrict__ incl,
                                                       int* __restrict__ blockSums, int N) {
    __shared__ int s[SCAN_B];
    int i = blockIdx.x * SCAN_B + threadIdx.x;
    int v = (i < N) ? deg[i] : 0;
    s[threadIdx.x] = v;
    __syncthreads();
#pragma unroll
    for (int off = 1; off < SCAN_B; off <<= 1) {
        int t = (threadIdx.x >= off) ? s[threadIdx.x - off] : 0;
        __syncthreads();
        s[threadIdx.x] += t;
        __syncthreads();
    }
    if (i < N) incl[i] = s[threadIdx.x];
    if (threadIdx.x == SCAN_B - 1) blockSums[blockIdx.x] = s[SCAN_B - 1];
}

__global__ __launch_bounds__(1024) void scan2_kernel(int* __restrict__ blockSums, int nb) {
    __shared__ int s[1024];
    int v = (threadIdx.x < nb) ? blockSums[threadIdx.x] : 0;
    s[threadIdx.x] = v;
    __syncthreads();
#pragma unroll
    for (int off = 1; off < 1024; off <<= 1) {
        int t = (threadIdx.x >= off) ? s[threadIdx.x - off] : 0;
        __syncthreads();
        s[threadIdx.x] += t;
        __syncthreads();
    }
    // write exclusive
    if (threadIdx.x < nb) blockSums[threadIdx.x] = (threadIdx.x > 0) ? s[threadIdx.x - 1] : 0;
}

__global__ void scan3_kernel(const int* __restrict__ incl, const int* __restrict__ deg,
                             const int* __restrict__ blockSums, int* __restrict__ rowstart,
                             int N, int E) {
    int i = blockIdx.x * blockDim.x + threadIdx.x;
    if (i < N) rowstart[i] = incl[i] - deg[i] + blockSums[i / SCAN_B];
    if (i == 0) rowstart[N] = E;
}

// ---------------- counting-sort scatter: elist[pos] = (src, norm) ----------------
__global__ void scatter_kernel(const int* __restrict__ src, const int* __restrict__ dst,
                               const int* __restrict__ rowstart, int* __restrict__ cursor,
                               int2* __restrict__ elist, const float* __restrict__ dinv, int E) {
    int e = blockIdx.x * blockDim.x + threadIdx.x;
    if (e >= E) return;
    int s = src[e], d = dst[e];
    int pos = rowstart[d] + atomicAdd(&cursor[d], 1);
    float nm = dinv[s] * dinv[d];
    elist[pos] = make_int2(s, __float_as_int(nm));
}

// ---------------- linear1: h = x @ W1   (x: [N,20], W1: [20,128]) ----------------
__global__ __launch_bounds__(HID) void linear1_kernel(const float* __restrict__ x,
                                                      const float* __restrict__ W,
                                                      float* __restrict__ h, int N, int IN) {
    __shared__ float Ws[20 * HID];
    __shared__ float xs[NPB1][20];
    for (int i = threadIdx.x; i < IN * HID; i += blockDim.x) Ws[i] = W[i];
    int n0 = blockIdx.x * NPB1;
    for (int i = threadIdx.x; i < NPB1 * IN; i += blockDim.x) {
        int m = i / IN, k = i % IN;
        int n = n0 + m;
        xs[m][k] = (n < N) ? x[(size_t)n * IN + k] : 0.f;
    }
    __syncthreads();
    int j = threadIdx.x;
    for (int m = 0; m < NPB1; ++m) {
        int n = n0 + m;
        if (n >= N) break;
        float acc = 0.f;
#pragma unroll 20
        for (int k = 0; k < 20; ++k) acc += xs[m][k] * Ws[k * HID + j];
        h[(size_t)n * HID + j] = acc;
    }
}

// ---------------- linear2: h2 = h @ W2   (W2: [128,128]) ----------------
__global__ __launch_bounds__(HID) void linear2_kernel(const float* __restrict__ hin,
                                                      const float* __restrict__ W,
                                                      float* __restrict__ hout, int N) {
    __shared__ float Ws[HID * HID];  // 64 KiB
    __shared__ float xs[NPB2][HID];
    for (int i = threadIdx.x; i < HID * HID; i += blockDim.x) Ws[i] = W[i];
    int n0 = blockIdx.x * NPB2;
    for (int i = threadIdx.x; i < NPB2 * HID; i += blockDim.x) {
        int m = i >> 7, k = i & 127;
        int n = n0 + m;
        xs[m][k] = (n < N) ? hin[(size_t)n * HID + k] : 0.f;
    }
    __syncthreads();
    int j = threadIdx.x;
    for (int m = 0; m < NPB2; ++m) {
        int n = n0 + m;
        if (n >= N) break;
        float acc = 0.f;
#pragma unroll 16
        for (int k = 0; k < HID; ++k) acc += xs[m][k] * Ws[k * HID + j];
        hout[(size_t)n * HID + j] = acc;
    }
}

// ---------------- CSR aggregation fused with self-loop + bias + relu ----------------
// 128 threads per dst node (2 nodes / 256-thread block); no atomics, no pre-zero.
__global__ __launch_bounds__(256) void csr_agg_kernel(const float* __restrict__ h,
                                                      float* __restrict__ outb,
                                                      const int* __restrict__ rowstart,
                                                      const int2* __restrict__ elist,
                                                      const float* __restrict__ dinv,
                                                      const float* __restrict__ bias,
                                                      int N) {
    int node = blockIdx.x * 2 + (threadIdx.x >> 7);
    if (node >= N) return;
    int j = threadIdx.x & 127;
    int beg = rowstart[node], end = rowstart[node + 1];
    float acc = 0.f;
    int e = beg;
    for (; e + 1 < end; e += 2) {
        int2 p0 = elist[e];
        int2 p1 = elist[e + 1];
        float a0 = h[(size_t)p0.x * HID + j];
        float a1 = h[(size_t)p1.x * HID + j];
        acc += a0 * __int_as_float(p0.y);
        acc += a1 * __int_as_float(p1.y);
    }
    if (e < end) {
        int2 p0 = elist[e];
        acc += h[(size_t)p0.x * HID + j] * __int_as_float(p0.y);
    }
    float di = dinv[node];
    float v = acc + h[(size_t)node * HID + j] * di * di + bias[j];
    outb[(size_t)node * HID + j] = fmaxf(v, 0.f);
}

// ---------------- pooling ----------------
__global__ void pool_kernel(const float* __restrict__ h, const int* __restrict__ batch,
                            float* __restrict__ pooled, int N) {
    int t = blockIdx.x * blockDim.x + threadIdx.x;
    if (t >= N * HID) return;
    int n = t >> 7, j = t & 127;
    atomicAdd(&pooled[(size_t)batch[n] * HID + j], h[t]);
}

__global__ void cnt_kernel(const int* __restrict__ batch, float* __restrict__ cnt, int N) {
    int i = blockIdx.x * blockDim.x + threadIdx.x;
    if (i < N) atomicAdd(&cnt[batch[i]], 1.f);
}

__global__ void mean_kernel(const float* __restrict__ pooled, const float* __restrict__ cnt,
                            float* __restrict__ meanp, int G) {
    int t = blockIdx.x * blockDim.x + threadIdx.x;
    if (t >= G * HID) return;
    int g = t >> 7;
    meanp[t] = pooled[t] / fmaxf(cnt[g], 1.f);
}

// ---------------- classifier: out = meanp @ Wc + bc ----------------
#define TILE_G 32
__global__ __launch_bounds__(256) void classifier_kernel(const float* __restrict__ meanp,
                                                         const float* __restrict__ Wc,
                                                         const float* __restrict__ bc,
                                                         float* __restrict__ out, int G, int OUT) {
    __shared__ float ps[TILE_G * HID];  // 16 KiB
    int g0 = blockIdx.y * TILE_G;
    for (int i = threadIdx.x; i < TILE_G * HID; i += blockDim.x) {
        int g = g0 + (i >> 7);
        ps[i] = (g < G) ? meanp[(size_t)g * HID + (i & 127)] : 0.f;
    }
    __syncthreads();
    int o = blockIdx.x * blockDim.x + threadIdx.x;
    if (o >= OUT) return;
    float acc[TILE_G];
#pragma unroll
    for (int g = 0; g < TILE_G; ++g) acc[g] = 0.f;
    for (int k = 0; k < HID; ++k) {
        float w = Wc[(size_t)k * OUT + o];
#pragma unroll
        for (int g = 0; g < TILE_G; ++g) acc[g] += ps[g * HID + k] * w;
    }
    float b = bc[o];
    for (int g = 0; g < TILE_G && (g0 + g) < G; ++g)
        out[(size_t)(g0 + g) * OUT + o] = acc[g] + b;
}

// ---------------- launch ----------------
extern "C" void kernel_launch(void* const* d_in, const int* in_sizes, int n_in,
                              void* d_out, int out_size, void* d_ws, size_t ws_size,
                              hipStream_t stream) {
    const float* x  = (const float*)d_in[0];
    const void*  ei = d_in[1];
    const void*  bt = d_in[2];
    const float* W1 = (const float*)d_in[3];
    const float* b1 = (const float*)d_in[4];
    const float* W2 = (const float*)d_in[5];
    const float* b2 = (const float*)d_in[6];
    const float* Wc = (const float*)d_in[7];
    const float* bc = (const float*)d_in[8];
    float* out = (float*)d_out;

    const int N   = in_sizes[2];
    const int E   = in_sizes[1] / 2;
    const int IN  = in_sizes[0] / N;
    const int OUT = in_sizes[8];
    const int G   = out_size / OUT;

    // workspace layout
    char* ws = (char*)d_ws;
    size_t off = 0;
    auto alloc = [&](size_t bytes) {
        size_t p = off;
        off += (bytes + 255) & ~(size_t)255;
        return p;
    };
    int*   idx32    = (int*)(ws + alloc((size_t)2 * E * 4));
    int*   batch32  = (int*)(ws + alloc((size_t)N * 4));
    int*   deg      = (int*)(ws + alloc((size_t)N * 4));
    float* dinv     = (float*)(ws + alloc((size_t)N * 4));
    int*   incl     = (int*)(ws + alloc((size_t)N * 4));
    int*   rowstart = (int*)(ws + alloc((size_t)(N + 1) * 4));
    int*   cursor   = (int*)(ws + alloc((size_t)N * 4));
    int*   blockSums= (int*)(ws + alloc((size_t)1024 * 4));
    int2*  elist    = (int2*)(ws + alloc((size_t)E * 8));
    float* bufA     = (float*)(ws + alloc((size_t)N * HID * 4));
    float* bufB     = (float*)(ws + alloc((size_t)N * HID * 4));
    float* pooled   = (float*)(ws + alloc((size_t)G * HID * 4));
    float* cnt      = (float*)(ws + alloc((size_t)G * 4));
    float* meanp    = (float*)(ws + alloc((size_t)G * HID * 4));
    int*   flag     = (int*)(ws + alloc(4));
    (void)ws_size;

    int* srcI = idx32;
    int* dstI = idx32 + E;

    const int B = 256;
    const int nb = (N + SCAN_B - 1) / SCAN_B;

    // 1. detect index dtype, convert to int32
    detect_kernel<<<1, 64, 0, stream>>>((const unsigned int*)ei, flag);
    cvt_kernel<<<(2 * E + B - 1) / B, B, 0, stream>>>(ei, idx32, 2 * E, flag);
    cvt_kernel<<<(N + B - 1) / B, B, 0, stream>>>(bt, batch32, N, flag);

    // 2. degrees (+1 self loop) -> dinv
    zero_kernel<<<256, B, 0, stream>>>((float4*)deg, (long long)N / 4);
    deg_kernel<<<(E + B - 1) / B, B, 0, stream>>>(dstI, deg, E);
    dinv_kernel<<<(N + B - 1) / B, B, 0, stream>>>(deg, dinv, N);

    // 3. CSR build: exclusive scan + counting-sort scatter
    scan1_kernel<<<nb, SCAN_B, 0, stream>>>(deg, incl, blockSums, N);
    scan2_kernel<<<1, 1024, 0, stream>>>(blockSums, nb);
    scan3_kernel<<<(N + B - 1) / B, B, 0, stream>>>(incl, deg, blockSums, rowstart, N, E);
    zero_kernel<<<256, B, 0, stream>>>((float4*)cursor, (long long)N / 4);
    scatter_kernel<<<(E + B - 1) / B, B, 0, stream>>>(srcI, dstI, rowstart, cursor, elist, dinv, E);

    // 4. layer 1
    linear1_kernel<<<(N + NPB1 - 1) / NPB1, HID, 0, stream>>>(x, W1, bufA, N, IN);
    csr_agg_kernel<<<(N + 1) / 2, 256, 0, stream>>>(bufA, bufB, rowstart, elist, dinv, b1, N);

    // 5. layer 2
    linear2_kernel<<<(N + NPB2 - 1) / NPB2, HID, 0, stream>>>(bufB, W2, bufA, N);
    csr_agg_kernel<<<(N + 1) / 2, 256, 0, stream>>>(bufA, bufB, rowstart, elist, dinv, b2, N);

    // 6. mean pool
    zero_kernel<<<64, B, 0, stream>>>((float4*)pooled, (long long)G * HID / 4);
    zero_kernel<<<1, B, 0, stream>>>((float4*)cnt, (long long)G / 4);
    pool_kernel<<<(N * HID + B - 1) / B, B, 0, stream>>>(bufB, batch32, pooled, N);
    cnt_kernel<<<(N + B - 1) / B, B, 0, stream>>>(batch32, cnt, N);
    mean_kernel<<<(G * HID + B - 1) / B, B, 0, stream>>>(pooled, cnt, meanp, G);

    // 7. classifier
    {
        dim3 grid((OUT + 255) / 256, (G + TILE_G - 1) / TILE_G);
        classifier_kernel<<<grid, 256, 0, stream>>>(meanp, Wc, bc, out, G, OUT);
    }
}